// Round 2
// baseline (493.715 us; speedup 1.0000x reference)
//
#include <hip/hip_runtime.h>

typedef unsigned short u16;
typedef __attribute__((ext_vector_type(8))) short short8;
typedef __attribute__((ext_vector_type(4))) float f32x4;

constexpr int BATCH = 8, CC = 128, CE = 256, DIM = 128, NTOK = 4096;

#define DEV static __device__ __forceinline__

DEV u16 f2bf(float f) {
    union { float f; unsigned u; } v; v.f = f;
    unsigned r = (v.u + 0x7fffu + ((v.u >> 16) & 1u)) >> 16;
    return (u16)r;
}
DEV float bf2f(u16 h) {
    union { unsigned u; float f; } v; v.u = ((unsigned)h) << 16;
    return v.f;
}

// ---------------------------------------------------------------------------
// Kernel 1: fused QKV projection. fp32 compute, bf16 outputs.
// Q,K stored [B][N][D]; V stored [B][D][N].
// ---------------------------------------------------------------------------
template <int CTOT, bool TRANS>
__device__ void proj_pass(const float* __restrict__ X, const float* __restrict__ W,
                          const float* __restrict__ bias, u16* __restrict__ dst,
                          int b, int nbase, float* sX, float* sW)
{
    const int tid = threadIdx.x;
    const int nl = tid & 15, cg = tid >> 4;
    const int n0 = nl * 4, d0 = cg * 8;

    float acc[4][8];
#pragma unroll
    for (int i = 0; i < 4; ++i)
#pragma unroll
        for (int j = 0; j < 8; ++j) acc[i][j] = 0.f;

    for (int cb = 0; cb < CTOT; cb += 64) {
        __syncthreads();
        // stage X chunk [64c][64n]  (coalesced rows)
#pragma unroll
        for (int i = 0; i < 16; ++i) {
            int idx = tid + 256 * i;
            int c = idx >> 6, n = idx & 63;
            sX[idx] = X[((size_t)b * CTOT + cb + c) * NTOK + nbase + n];
        }
        // stage W chunk transposed [64c][128d]
#pragma unroll
        for (int i = 0; i < 32; ++i) {
            int idx = tid + 256 * i;
            int c = idx >> 7, d = idx & 127;
            sW[c * 128 + d] = W[(size_t)d * CTOT + cb + c];
        }
        __syncthreads();
#pragma unroll 2
        for (int c = 0; c < 64; ++c) {
            const float4 x  = *(const float4*)&sX[c * 64 + n0];
            const float4 wa = *(const float4*)&sW[c * 128 + d0];
            const float4 wb = *(const float4*)&sW[c * 128 + d0 + 4];
#pragma unroll
            for (int i = 0; i < 4; ++i) {
                const float xv = (&x.x)[i];
                acc[i][0] += xv * wa.x; acc[i][1] += xv * wa.y;
                acc[i][2] += xv * wa.z; acc[i][3] += xv * wa.w;
                acc[i][4] += xv * wb.x; acc[i][5] += xv * wb.y;
                acc[i][6] += xv * wb.z; acc[i][7] += xv * wb.w;
            }
        }
    }
    float bb[8];
#pragma unroll
    for (int j = 0; j < 8; ++j) bb[j] = bias[d0 + j];

    if (!TRANS) {
#pragma unroll
        for (int i = 0; i < 4; ++i) {
            short8 o;
#pragma unroll
            for (int j = 0; j < 8; ++j) o[j] = (short)f2bf(acc[i][j] + bb[j]);
            *(short8*)&dst[((size_t)b * NTOK + nbase + n0 + i) * DIM + d0] = o;
        }
    } else {
#pragma unroll
        for (int j = 0; j < 8; ++j) {
            ushort4 o;
            o.x = f2bf(acc[0][j] + bb[j]); o.y = f2bf(acc[1][j] + bb[j]);
            o.z = f2bf(acc[2][j] + bb[j]); o.w = f2bf(acc[3][j] + bb[j]);
            *(ushort4*)&dst[((size_t)b * DIM + d0 + j) * NTOK + nbase + n0] = o;
        }
    }
}

__global__ __launch_bounds__(256)
void qkv_proj_kernel(const float* __restrict__ cape, const float* __restrict__ era5,
                     const float* __restrict__ Wq, const float* __restrict__ bq,
                     const float* __restrict__ Wk, const float* __restrict__ bk,
                     const float* __restrict__ Wv, const float* __restrict__ bv,
                     u16* __restrict__ Qb, u16* __restrict__ Kb, u16* __restrict__ Vb)
{
    __shared__ __align__(16) float sX[64 * 64];
    __shared__ __align__(16) float sW[64 * 128];
    const int b = blockIdx.y;
    const int nbase = blockIdx.x * 64;
    proj_pass<CC, false>(cape, Wq, bq, Qb, b, nbase, sX, sW);
    proj_pass<CE, false>(era5, Wk, bk, Kb, b, nbase, sX, sW);
    proj_pass<CE, true >(era5, Wv, bv, Vb, b, nbase, sX, sW);
}

// ---------------------------------------------------------------------------
// Kernel 2: flash attention. Q,K [B][N][D] bf16, V [B][D][N] bf16 -> AO [B][N][D] bf16.
// 4 waves x 16 q-rows, KBLK=64, mfma_f32_16x16x32_bf16.
// Round 2: defer-max (T13), lane-local l partials, reg-prefetch staging (T14),
//          v_cvt_pk_bf16_f32 for P, setprio (T5).
// ---------------------------------------------------------------------------
__global__ __launch_bounds__(256)
void attn_kernel(const u16* __restrict__ Qg, const u16* __restrict__ Kg,
                 const u16* __restrict__ Vg, u16* __restrict__ AO)
{
    __shared__ __align__(16) u16 sK[64 * 128];      // row k, 16B-chunk swizzle c^=(k&7)
    __shared__ __align__(16) u16 sV[128 * 64];      // row d, chunk swizzle c^=(d&7)
    __shared__ __align__(16) u16 sP[4][16][72];     // per-wave P tile, stride 72 (pad 8)

    const int tid = threadIdx.x;
    const int b = blockIdx.y;
    const int qbase = blockIdx.x * 64;
    const int lane = tid & 63, w = tid >> 6;
    const int col = lane & 15, g = lane >> 4;

    const float kScale = 0.088388347648318447f * 1.4426950408889634f; // 1/sqrt(128)*log2(e)

    const u16* Kbase = Kg + (size_t)b * NTOK * DIM;
    const u16* Vbase = Vg + (size_t)b * DIM * NTOK;
    const int kr = tid >> 4, kc = tid & 15;   // K staging coords (row, 16B chunk)
    const int vr = tid >> 3, vc = tid & 7;    // V staging coords

    uint4 kpf[4], vpf[4];                     // prefetch registers

    // ---- stage Q tile (through sK buffer, swizzled) and read A-frags
#pragma unroll
    for (int i = 0; i < 4; ++i) {
        int row = kr + 16 * i;
        uint4 v = *(const uint4*)&Qg[((size_t)b * NTOK + qbase + row) * DIM + kc * 8];
        *(uint4*)&sK[row * 128 + ((kc ^ (row & 7)) * 8)] = v;
    }
    // issue tile-0 K/V loads while Q staging settles
#pragma unroll
    for (int i = 0; i < 4; ++i)
        kpf[i] = *(const uint4*)&Kbase[(size_t)(kr + 16 * i) * DIM + kc * 8];
#pragma unroll
    for (int i = 0; i < 4; ++i)
        vpf[i] = *(const uint4*)&Vbase[(size_t)(vr + 32 * i) * NTOK + vc * 8];

    __syncthreads();
    short8 aQ[4];
    {
        const int qr = w * 16 + col;
#pragma unroll
        for (int dc = 0; dc < 4; ++dc) {
            int c2 = (dc * 4 + g) ^ (qr & 7);
            aQ[dc] = *(const short8*)&sK[qr * 128 + c2 * 8];
        }
    }
    __syncthreads();
    // commit tile 0
#pragma unroll
    for (int i = 0; i < 4; ++i) {
        int row = kr + 16 * i;
        *(uint4*)&sK[row * 128 + ((kc ^ (row & 7)) * 8)] = kpf[i];
    }
#pragma unroll
    for (int i = 0; i < 4; ++i) {
        int dr = vr + 32 * i;
        *(uint4*)&sV[dr * 64 + ((vc ^ (dr & 7)) * 8)] = vpf[i];
    }
    __syncthreads();

    f32x4 O[8];
#pragma unroll
    for (int i = 0; i < 8; ++i)
#pragma unroll
        for (int r = 0; r < 4; ++r) O[i][r] = 0.f;
    float m_run[4], l_part[4];
#pragma unroll
    for (int r = 0; r < 4; ++r) { m_run[r] = -1e30f; l_part[r] = 0.f; }

    for (int t = 0; t < NTOK / 64; ++t) {
        // ---- issue next-tile loads (latency hides under this tile's compute)
        if (t + 1 < NTOK / 64) {
#pragma unroll
            for (int i = 0; i < 4; ++i)
                kpf[i] = *(const uint4*)&Kbase[(size_t)((t + 1) * 64 + kr + 16 * i) * DIM + kc * 8];
#pragma unroll
            for (int i = 0; i < 4; ++i)
                vpf[i] = *(const uint4*)&Vbase[(size_t)(vr + 32 * i) * NTOK + (t + 1) * 64 + vc * 8];
        }

        // ---- S = Q K^T  (4 k-subtiles x 4 d-chunks)
        f32x4 S[4];
#pragma unroll
        for (int s = 0; s < 4; ++s)
#pragma unroll
            for (int r = 0; r < 4; ++r) S[s][r] = 0.f;
        __builtin_amdgcn_s_setprio(1);
#pragma unroll
        for (int s = 0; s < 4; ++s) {
            const int krow = s * 16 + col;
#pragma unroll
            for (int dc = 0; dc < 4; ++dc) {
                int c2 = (dc * 4 + g) ^ (krow & 7);
                short8 bK = *(const short8*)&sK[krow * 128 + c2 * 8];
                S[s] = __builtin_amdgcn_mfma_f32_16x16x32_bf16(aQ[dc], bK, S[s], 0, 0, 0);
            }
        }
        __builtin_amdgcn_s_setprio(0);

        // ---- online softmax, defer-max (T13). Lane (g,col) owns q rows 4g..4g+3.
        float lmax[4];
#pragma unroll
        for (int r = 0; r < 4; ++r)
            lmax[r] = fmaxf(fmaxf(S[0][r], S[1][r]), fmaxf(S[2][r], S[3][r])) * kScale;

        bool ok = (lmax[0] <= m_run[0] + 8.f) & (lmax[1] <= m_run[1] + 8.f) &
                  (lmax[2] <= m_run[2] + 8.f) & (lmax[3] <= m_run[3] + 8.f);
        if (!__all(ok)) {
            // full max-update path (rare: ~1/64 tiles)
            float mx[4];
#pragma unroll
            for (int r = 0; r < 4; ++r) mx[r] = lmax[r];
#pragma unroll
            for (int off = 1; off < 16; off <<= 1)
#pragma unroll
                for (int r = 0; r < 4; ++r)
                    mx[r] = fmaxf(mx[r], __shfl_xor(mx[r], off, 64));
#pragma unroll
            for (int r = 0; r < 4; ++r) {
                float mn = fmaxf(m_run[r], mx[r]);
                float fs = exp2f(m_run[r] - mn);
                m_run[r] = mn;
                l_part[r] *= fs;
#pragma unroll
                for (int i = 0; i < 8; ++i) O[i][r] *= fs;
            }
        }

        float P[4][4];
#pragma unroll
        for (int s = 0; s < 4; ++s)
#pragma unroll
            for (int r = 0; r < 4; ++r)
                P[s][r] = exp2f(fmaf(S[s][r], kScale, -m_run[r]));
#pragma unroll
        for (int r = 0; r < 4; ++r)
            l_part[r] += (P[0][r] + P[1][r]) + (P[2][r] + P[3][r]);

        // ---- write P (bf16, packed cvt) to per-wave LDS tile [16q][64k]
        {
            u16* sPw = &sP[w][0][0];
            const int kcol = col;  // within-subtile col
#pragma unroll
            for (int s = 0; s < 4; ++s) {
                unsigned pk01, pk23;
                asm("v_cvt_pk_bf16_f32 %0, %1, %2" : "=v"(pk01) : "v"(P[s][0]), "v"(P[s][1]));
                asm("v_cvt_pk_bf16_f32 %0, %1, %2" : "=v"(pk23) : "v"(P[s][2]), "v"(P[s][3]));
                const int kk = s * 16 + kcol;
                sPw[(g * 4 + 0) * 72 + kk] = (u16)pk01;
                sPw[(g * 4 + 1) * 72 + kk] = (u16)(pk01 >> 16);
                sPw[(g * 4 + 2) * 72 + kk] = (u16)pk23;
                sPw[(g * 4 + 3) * 72 + kk] = (u16)(pk23 >> 16);
            }
        }

        // ---- O += P V
#pragma unroll
        for (int kc2 = 0; kc2 < 2; ++kc2) {
            short8 aP = *(const short8*)&sP[w][col][kc2 * 32 + g * 8];
            __builtin_amdgcn_s_setprio(1);
#pragma unroll
            for (int dc2 = 0; dc2 < 8; ++dc2) {
                const int dr = dc2 * 16 + col;
                int c2 = (kc2 * 4 + g) ^ (dr & 7);
                short8 bV = *(const short8*)&sV[dr * 64 + c2 * 8];
                O[dc2] = __builtin_amdgcn_mfma_f32_16x16x32_bf16(aP, bV, O[dc2], 0, 0, 0);
            }
            __builtin_amdgcn_s_setprio(0);
        }
        __syncthreads();

        // ---- commit prefetched tile t+1 to LDS
        if (t + 1 < NTOK / 64) {
#pragma unroll
            for (int i = 0; i < 4; ++i) {
                int row = kr + 16 * i;
                *(uint4*)&sK[row * 128 + ((kc ^ (row & 7)) * 8)] = kpf[i];
            }
#pragma unroll
            for (int i = 0; i < 4; ++i) {
                int dr = vr + 32 * i;
                *(uint4*)&sV[dr * 64 + ((vc ^ (dr & 7)) * 8)] = vpf[i];
            }
        }
        __syncthreads();
    }

    // ---- epilogue: reduce l over the 16 cols, normalize, store AO[b][q][d]
    float l[4];
#pragma unroll
    for (int r = 0; r < 4; ++r) l[r] = l_part[r];
#pragma unroll
    for (int off = 1; off < 16; off <<= 1)
#pragma unroll
        for (int r = 0; r < 4; ++r) l[r] += __shfl_xor(l[r], off, 64);
    float inv[4];
#pragma unroll
    for (int r = 0; r < 4; ++r) inv[r] = 1.f / l[r];
#pragma unroll
    for (int dc2 = 0; dc2 < 8; ++dc2)
#pragma unroll
        for (int r = 0; r < 4; ++r) {
            int q = qbase + w * 16 + g * 4 + r;
            AO[((size_t)b * NTOK + q) * DIM + dc2 * 16 + col] = f2bf(O[dc2][r] * inv[r]);
        }
}

// ---------------------------------------------------------------------------
// Kernel 3: output projection. out[b][co][n] = Wo @ AO[b][n][:] + bo
// ---------------------------------------------------------------------------
__global__ __launch_bounds__(256)
void oproj_kernel(const u16* __restrict__ AO, const float* __restrict__ Wo,
                  const float* __restrict__ bo, float* __restrict__ Out)
{
    __shared__ __align__(16) u16 sA[128 * 72];   // [d][n] transposed, stride 72
    __shared__ __align__(16) u16 sW[128 * 128];  // [d][co], Wo as bf16

    const int tid = threadIdx.x;
    const int b = blockIdx.y;
    const int nbase = blockIdx.x * 64;

    // stage Wo transposed (coalesced global read; LDS write conflicts are one-time)
#pragma unroll 4
    for (int i = 0; i < 64; ++i) {
        int idx = tid + 256 * i;
        int d = idx & 127, co = idx >> 7;
        sW[d * 128 + co] = f2bf(Wo[(size_t)co * DIM + d]);
    }
    // stage AO tile transposed [d][n]
#pragma unroll
    for (int i = 0; i < 4; ++i) {
        int idx = tid + 256 * i;
        int c = idx & 15, n = idx >> 4;
        uint4 v = *(const uint4*)&AO[((size_t)b * NTOK + nbase + n) * DIM + c * 8];
        unsigned tmp[4] = {v.x, v.y, v.z, v.w};
#pragma unroll
        for (int j = 0; j < 8; ++j)
            sA[(c * 8 + j) * 72 + n] = (u16)(tmp[j >> 1] >> ((j & 1) * 16));
    }
    __syncthreads();

    const int nl = tid & 15, cg = tid >> 4;
    const int n0 = nl * 4, co0 = cg * 8;
    float acc[4][8];
#pragma unroll
    for (int i = 0; i < 4; ++i)
#pragma unroll
        for (int j = 0; j < 8; ++j) acc[i][j] = 0.f;

#pragma unroll 4
    for (int d = 0; d < 128; ++d) {
        ushort4 xs = *(const ushort4*)&sA[d * 72 + n0];
        short8 wv  = *(const short8*)&sW[d * 128 + co0];
        float x[4] = {bf2f(xs.x), bf2f(xs.y), bf2f(xs.z), bf2f(xs.w)};
        float wf[8];
#pragma unroll
        for (int j = 0; j < 8; ++j) wf[j] = bf2f((u16)wv[j]);
#pragma unroll
        for (int i = 0; i < 4; ++i)
#pragma unroll
            for (int j = 0; j < 8; ++j) acc[i][j] += x[i] * wf[j];
    }

#pragma unroll
    for (int j = 0; j < 8; ++j) {
        float bb = bo[co0 + j];
        float4 o = {acc[0][j] + bb, acc[1][j] + bb, acc[2][j] + bb, acc[3][j] + bb};
        *(float4*)&Out[((size_t)b * DIM + co0 + j) * NTOK + nbase + n0] = o;
    }
}

// ---------------------------------------------------------------------------
extern "C" void kernel_launch(void* const* d_in, const int* in_sizes, int n_in,
                              void* d_out, int out_size, void* d_ws, size_t ws_size,
                              hipStream_t stream)
{
    const float* cape = (const float*)d_in[0];
    const float* era5 = (const float*)d_in[1];
    const float* Wq = (const float*)d_in[2];
    const float* bq = (const float*)d_in[3];
    const float* Wk = (const float*)d_in[4];
    const float* bk = (const float*)d_in[5];
    const float* Wv = (const float*)d_in[6];
    const float* bv = (const float*)d_in[7];
    const float* Wo = (const float*)d_in[8];
    const float* bo = (const float*)d_in[9];

    u16* Qb = (u16*)d_ws;
    u16* Kb = Qb + (size_t)BATCH * NTOK * DIM;
    u16* Vb = Kb + (size_t)BATCH * NTOK * DIM;
    u16* AO = Vb + (size_t)BATCH * NTOK * DIM;

    dim3 grid(NTOK / 64, BATCH), blk(256);
    hipLaunchKernelGGL(qkv_proj_kernel, grid, blk, 0, stream,
                       cape, era5, Wq, bq, Wk, bk, Wv, bv, Qb, Kb, Vb);
    hipLaunchKernelGGL(attn_kernel, grid, blk, 0, stream, Qb, Kb, Vb, AO);
    hipLaunchKernelGGL(oproj_kernel, grid, blk, 0, stream, AO, Wo, bo, (float*)d_out);
}

// Round 3
// 276.175 us; speedup vs baseline: 1.7877x; 1.7877x over previous
//
#include <hip/hip_runtime.h>

typedef unsigned short u16;
typedef __attribute__((ext_vector_type(8))) short short8;
typedef __attribute__((ext_vector_type(4))) float f32x4;
typedef __attribute__((ext_vector_type(16))) float f32x16;

constexpr int BATCH = 8, CC = 128, CE = 256, DIM = 128, NTOK = 4096;
constexpr int KSPLIT = 2, KTILES = NTOK / KSPLIT / 64;   // 32 tiles of 64 per wg

#define DEV static __device__ __forceinline__

DEV u16 f2bf(float f) {
    union { float f; unsigned u; } v; v.f = f;
    unsigned r = (v.u + 0x7fffu + ((v.u >> 16) & 1u)) >> 16;
    return (u16)r;
}
DEV float bf2f(u16 h) {
    union { unsigned u; float f; } v; v.u = ((unsigned)h) << 16;
    return v.f;
}
DEV short8 mk8(unsigned a, unsigned b, unsigned c, unsigned d) {
    union { unsigned u[4]; short8 s; } t; t.u[0] = a; t.u[1] = b; t.u[2] = c; t.u[3] = d;
    return t.s;
}

// ---------------------------------------------------------------------------
// Kernel 1: fused QKV projection (unchanged this round).
// Q,K stored [B][N][D] bf16; V stored [B][D][N] bf16.
// ---------------------------------------------------------------------------
template <int CTOT, bool TRANS>
__device__ void proj_pass(const float* __restrict__ X, const float* __restrict__ W,
                          const float* __restrict__ bias, u16* __restrict__ dst,
                          int b, int nbase, float* sX, float* sW)
{
    const int tid = threadIdx.x;
    const int nl = tid & 15, cg = tid >> 4;
    const int n0 = nl * 4, d0 = cg * 8;

    float acc[4][8];
#pragma unroll
    for (int i = 0; i < 4; ++i)
#pragma unroll
        for (int j = 0; j < 8; ++j) acc[i][j] = 0.f;

    for (int cb = 0; cb < CTOT; cb += 64) {
        __syncthreads();
#pragma unroll
        for (int i = 0; i < 16; ++i) {
            int idx = tid + 256 * i;
            int c = idx >> 6, n = idx & 63;
            sX[idx] = X[((size_t)b * CTOT + cb + c) * NTOK + nbase + n];
        }
#pragma unroll
        for (int i = 0; i < 32; ++i) {
            int idx = tid + 256 * i;
            int c = idx >> 7, d = idx & 127;
            sW[c * 128 + d] = W[(size_t)d * CTOT + cb + c];
        }
        __syncthreads();
#pragma unroll 2
        for (int c = 0; c < 64; ++c) {
            const float4 x  = *(const float4*)&sX[c * 64 + n0];
            const float4 wa = *(const float4*)&sW[c * 128 + d0];
            const float4 wb = *(const float4*)&sW[c * 128 + d0 + 4];
#pragma unroll
            for (int i = 0; i < 4; ++i) {
                const float xv = (&x.x)[i];
                acc[i][0] += xv * wa.x; acc[i][1] += xv * wa.y;
                acc[i][2] += xv * wa.z; acc[i][3] += xv * wa.w;
                acc[i][4] += xv * wb.x; acc[i][5] += xv * wb.y;
                acc[i][6] += xv * wb.z; acc[i][7] += xv * wb.w;
            }
        }
    }
    float bb[8];
#pragma unroll
    for (int j = 0; j < 8; ++j) bb[j] = bias[d0 + j];

    if (!TRANS) {
#pragma unroll
        for (int i = 0; i < 4; ++i) {
            short8 o;
#pragma unroll
            for (int j = 0; j < 8; ++j) o[j] = (short)f2bf(acc[i][j] + bb[j]);
            *(short8*)&dst[((size_t)b * NTOK + nbase + n0 + i) * DIM + d0] = o;
        }
    } else {
#pragma unroll
        for (int j = 0; j < 8; ++j) {
            ushort4 o;
            o.x = f2bf(acc[0][j] + bb[j]); o.y = f2bf(acc[1][j] + bb[j]);
            o.z = f2bf(acc[2][j] + bb[j]); o.w = f2bf(acc[3][j] + bb[j]);
            *(ushort4*)&dst[((size_t)b * DIM + d0 + j) * NTOK + nbase + n0] = o;
        }
    }
}

__global__ __launch_bounds__(256)
void qkv_proj_kernel(const float* __restrict__ cape, const float* __restrict__ era5,
                     const float* __restrict__ Wq, const float* __restrict__ bq,
                     const float* __restrict__ Wk, const float* __restrict__ bk,
                     const float* __restrict__ Wv, const float* __restrict__ bv,
                     u16* __restrict__ Qb, u16* __restrict__ Kb, u16* __restrict__ Vb)
{
    __shared__ __align__(16) float sX[64 * 64];
    __shared__ __align__(16) float sW[64 * 128];
    const int b = blockIdx.y;
    const int nbase = blockIdx.x * 64;
    proj_pass<CC, false>(cape, Wq, bq, Qb, b, nbase, sX, sW);
    proj_pass<CE, false>(era5, Wk, bk, Kb, b, nbase, sX, sW);
    proj_pass<CE, true >(era5, Wv, bv, Vb, b, nbase, sX, sW);
}

// ---------------------------------------------------------------------------
// Kernel 2: flash attention, 32x32 MFMA, swapped QK^T, split-K, no-max softmax.
// 2 waves/block, 32 q-rows per wave (QBLK=64), KVBLK=64.
// S^T = mfma(K, Q): lane owns q-col = lane&31; 32 k-values in regs.
// P -> PV A-frag via cvt_pk + v_permlane32_swap (no LDS round-trip).
// Outputs UNNORMALIZED O partial (bf16) + l partial (f32); combined in oproj.
// ---------------------------------------------------------------------------
__global__ __launch_bounds__(128)
void attn_kernel(const u16* __restrict__ Qb, const u16* __restrict__ Kb,
                 const u16* __restrict__ Vb, u16* __restrict__ Op,
                 float* __restrict__ Lp)
{
    __shared__ __align__(16) u16 sK[64 * 128];   // [ktok][d], 16B chunk at pos c^(ktok&7)
    __shared__ __align__(16) u16 sV[128 * 64];   // [d][ktok], 16B chunk at pos c^(d&7)

    const int tid = threadIdx.x;
    const int lane = tid & 63, wv = tid >> 6;
    const int l31 = lane & 31, half = lane >> 5;

    // XCD-aware decode: consecutive dispatch ids land on the same XCD's share
    const int lin = blockIdx.x;
    const int swz = (lin & 7) * 128 + (lin >> 3);
    const int b = swz >> 7;
    const int rem = swz & 127;
    const int ks = rem >> 6;
    const int qtile = rem & 63;
    const int qbase = qtile * 64 + wv * 32;
    const int kbase = ks * (NTOK / KSPLIT);

    const float kScale = 0.088388347648318447f * 1.4426950408889634f; // 128^-0.5 * log2(e)

    // ---- Q fragments direct from global (B-frag of swapped QK^T):
    // lane holds Q[q = qbase + l31][d = s*16 + half*8 .. +8]
    short8 aQ[8];
    {
        const u16* qrow = Qb + ((size_t)b * NTOK + qbase + l31) * DIM + half * 8;
#pragma unroll
        for (int s = 0; s < 8; ++s) aQ[s] = *(const short8*)&qrow[s * 16];
    }

    f32x16 O[4];
#pragma unroll
    for (int i = 0; i < 4; ++i)
#pragma unroll
        for (int r = 0; r < 16; ++r) O[i][r] = 0.f;
    float l_part = 0.f;

    const u16* Kbat = Kb + (size_t)b * NTOK * DIM;
    const u16* Vbat = Vb + (size_t)b * DIM * NTOK;

    for (int t = 0; t < KTILES; ++t) {
        // ---- async stage K tile [64][128] (this wave: rows wv*32..wv*32+31)
        {
            const u16* kb0 = Kbat + (size_t)(kbase + t * 64) * DIM;
#pragma unroll
            for (int i = 0; i < 8; ++i) {
                const int row = wv * 32 + i * 4 + (lane >> 4);
                const int p = lane & 15;
                const u16* g = kb0 + (size_t)row * DIM + ((p ^ (row & 7)) * 8);
                __builtin_amdgcn_global_load_lds(
                    (const __attribute__((address_space(1))) unsigned int*)g,
                    (__attribute__((address_space(3))) unsigned int*)&sK[(wv * 8 + i) * 512],
                    16, 0, 0);
            }
        }
        // ---- async stage V tile [128][64] (this wave: d-rows wv*64..wv*64+63)
        {
            const u16* vb0 = Vbat + kbase + t * 64;
#pragma unroll
            for (int i = 0; i < 8; ++i) {
                const int row = wv * 64 + i * 8 + (lane >> 3);
                const int p = lane & 7;
                const u16* g = vb0 + (size_t)row * NTOK + ((p ^ (row & 7)) * 8);
                __builtin_amdgcn_global_load_lds(
                    (const __attribute__((address_space(1))) unsigned int*)g,
                    (__attribute__((address_space(3))) unsigned int*)&sV[(wv * 8 + i) * 512],
                    16, 0, 0);
            }
        }
        __syncthreads();   // drains vmcnt -> tiles ready

        // ---- S^T = K Q^T : S[kblk] rows = ktok (reg pattern), cols = q (lane)
        f32x16 S0, S1;
#pragma unroll
        for (int r = 0; r < 16; ++r) { S0[r] = 0.f; S1[r] = 0.f; }
        __builtin_amdgcn_s_setprio(1);
#pragma unroll
        for (int s = 0; s < 8; ++s) {
            const int pos = (((s * 2 + half) ^ (l31 & 7)) * 8);
            short8 k0 = *(const short8*)&sK[l31 * 128 + pos];
            short8 k1 = *(const short8*)&sK[(32 + l31) * 128 + pos];
            S0 = __builtin_amdgcn_mfma_f32_32x32x16_bf16(k0, aQ[s], S0, 0, 0, 0);
            S1 = __builtin_amdgcn_mfma_f32_32x32x16_bf16(k1, aQ[s], S1, 0, 0, 0);
        }
        __builtin_amdgcn_s_setprio(0);

        // ---- softmax (no max tracking: |S*scale| < 1 statically) + bf16 pack
        // group m (k in [8m, 8m+8)): lane's own 4 values at positions (reg&3)+4*half
        unsigned xm[8], ym[8];
#define SM_GROUP(m, Sb)                                                              \
        {                                                                            \
            float p0 = exp2f(Sb[(m & 3) * 4 + 0] * kScale);                          \
            float p1 = exp2f(Sb[(m & 3) * 4 + 1] * kScale);                          \
            float p2 = exp2f(Sb[(m & 3) * 4 + 2] * kScale);                          \
            float p3 = exp2f(Sb[(m & 3) * 4 + 3] * kScale);                          \
            l_part += (p0 + p1) + (p2 + p3);                                         \
            asm("v_cvt_pk_bf16_f32 %0, %1, %2" : "=v"(xm[m]) : "v"(p0), "v"(p1));    \
            asm("v_cvt_pk_bf16_f32 %0, %1, %2" : "=v"(ym[m]) : "v"(p2), "v"(p3));    \
        }
        SM_GROUP(0, S0) SM_GROUP(1, S0) SM_GROUP(2, S0) SM_GROUP(3, S0)
        SM_GROUP(4, S1) SM_GROUP(5, S1) SM_GROUP(6, S1) SM_GROUP(7, S1)
#undef SM_GROUP

        // ---- redistribute halves: build PV A-frags (A[q=lane&31][k contiguous 8])
        short8 pa[4];
#pragma unroll
        for (int s2 = 0; s2 < 4; ++s2) {
            unsigned xa = xm[2 * s2], xb = xm[2 * s2 + 1];
            unsigned ya = ym[2 * s2], yb = ym[2 * s2 + 1];
            asm("v_permlane32_swap_b32 %0, %1" : "+v"(xa), "+v"(xb));
            asm("v_permlane32_swap_b32 %0, %1" : "+v"(ya), "+v"(yb));
            pa[s2] = mk8(xa, ya, xb, yb);
        }

        // ---- O += P V
        __builtin_amdgcn_s_setprio(1);
#pragma unroll
        for (int dblk = 0; dblk < 4; ++dblk) {
            const int vrow = dblk * 32 + l31;
#pragma unroll
            for (int s2 = 0; s2 < 4; ++s2) {
                short8 v = *(const short8*)&sV[vrow * 64 + (((s2 * 2 + half) ^ (l31 & 7)) * 8)];
                O[dblk] = __builtin_amdgcn_mfma_f32_32x32x16_bf16(pa[s2], v, O[dblk], 0, 0, 0);
            }
        }
        __builtin_amdgcn_s_setprio(0);
        __syncthreads();   // reads done before next tile overwrites
    }

    // ---- epilogue: store UNNORMALIZED partials
    float l_tot = l_part + __shfl_xor(l_part, 32, 64);
    if (half == 0)
        Lp[(size_t)(ks * BATCH + b) * NTOK + qbase + l31] = l_tot;

    u16* obase = Op + ((size_t)(ks * BATCH + b) * NTOK + qbase) * DIM;
#pragma unroll
    for (int dblk = 0; dblk < 4; ++dblk)
#pragma unroll
        for (int r = 0; r < 16; ++r) {
            const int q = (r & 3) + 8 * (r >> 2) + 4 * half;
            obase[(size_t)q * DIM + dblk * 32 + l31] = f2bf(O[dblk][r]);
        }
}

// ---------------------------------------------------------------------------
// Kernel 3: combine split-K partials + output projection.
// out[b][co][n] = Wo @ ((O0+O1)/(l0+l1)) + bo
// ---------------------------------------------------------------------------
__global__ __launch_bounds__(256)
void oproj_kernel(const u16* __restrict__ Op, const float* __restrict__ Lp,
                  const float* __restrict__ Wo, const float* __restrict__ bo,
                  float* __restrict__ Out)
{
    __shared__ __align__(16) u16 sA[128 * 72];   // [d][n] transposed, stride 72
    __shared__ __align__(16) u16 sW[128 * 128];  // [d][co]

    const int tid = threadIdx.x;
    const int b = blockIdx.y;
    const int nbase = blockIdx.x * 64;

#pragma unroll 4
    for (int i = 0; i < 64; ++i) {
        int idx = tid + 256 * i;
        int d = idx & 127, co = idx >> 7;
        sW[d * 128 + co] = f2bf(Wo[(size_t)co * DIM + d]);
    }
    // stage combined/normalized AO tile transposed [d][n]
#pragma unroll
    for (int i = 0; i < 4; ++i) {
        int idx = tid + 256 * i;
        int c = idx & 15, n = idx >> 4;
        const size_t r0 = ((size_t)b * NTOK + nbase + n) * DIM + c * 8;
        const size_t r1 = ((size_t)(BATCH + b) * NTOK + nbase + n) * DIM + c * 8;
        uint4 v0 = *(const uint4*)&Op[r0];
        uint4 v1 = *(const uint4*)&Op[r1];
        float l = Lp[(size_t)b * NTOK + nbase + n] +
                  Lp[(size_t)(BATCH + b) * NTOK + nbase + n];
        float inv = 1.f / l;
        unsigned t0[4] = {v0.x, v0.y, v0.z, v0.w};
        unsigned t1[4] = {v1.x, v1.y, v1.z, v1.w};
#pragma unroll
        for (int j = 0; j < 8; ++j) {
            float a = bf2f((u16)(t0[j >> 1] >> ((j & 1) * 16)));
            float bq_ = bf2f((u16)(t1[j >> 1] >> ((j & 1) * 16)));
            sA[(c * 8 + j) * 72 + n] = f2bf((a + bq_) * inv);
        }
    }
    __syncthreads();

    const int nl = tid & 15, cg = tid >> 4;
    const int n0 = nl * 4, co0 = cg * 8;
    float acc[4][8];
#pragma unroll
    for (int i = 0; i < 4; ++i)
#pragma unroll
        for (int j = 0; j < 8; ++j) acc[i][j] = 0.f;

#pragma unroll 4
    for (int d = 0; d < 128; ++d) {
        ushort4 xs = *(const ushort4*)&sA[d * 72 + n0];
        short8 wvv = *(const short8*)&sW[d * 128 + co0];
        float x[4] = {bf2f(xs.x), bf2f(xs.y), bf2f(xs.z), bf2f(xs.w)};
        float wf[8];
#pragma unroll
        for (int j = 0; j < 8; ++j) wf[j] = bf2f((u16)wvv[j]);
#pragma unroll
        for (int i = 0; i < 4; ++i)
#pragma unroll
            for (int j = 0; j < 8; ++j) acc[i][j] += x[i] * wf[j];
    }

#pragma unroll
    for (int j = 0; j < 8; ++j) {
        float bb = bo[co0 + j];
        float4 o = {acc[0][j] + bb, acc[1][j] + bb, acc[2][j] + bb, acc[3][j] + bb};
        *(float4*)&Out[((size_t)b * DIM + co0 + j) * NTOK + nbase + n0] = o;
    }
}

// ---------------------------------------------------------------------------
extern "C" void kernel_launch(void* const* d_in, const int* in_sizes, int n_in,
                              void* d_out, int out_size, void* d_ws, size_t ws_size,
                              hipStream_t stream)
{
    const float* cape = (const float*)d_in[0];
    const float* era5 = (const float*)d_in[1];
    const float* Wq = (const float*)d_in[2];
    const float* bq = (const float*)d_in[3];
    const float* Wk = (const float*)d_in[4];
    const float* bk = (const float*)d_in[5];
    const float* Wv = (const float*)d_in[6];
    const float* bv = (const float*)d_in[7];
    const float* Wo = (const float*)d_in[8];
    const float* bo = (const float*)d_in[9];

    const size_t QKV = (size_t)BATCH * NTOK * DIM;   // 4.19M elements
    u16* Qb = (u16*)d_ws;
    u16* Kb = Qb + QKV;
    u16* Vb = Kb + QKV;
    u16* Op = Vb + QKV;                    // KSPLIT * QKV bf16 (unnormalized partials)
    float* Lp = (float*)(Op + (size_t)KSPLIT * QKV);   // KSPLIT * B * N f32

    dim3 blk(256);
    hipLaunchKernelGGL(qkv_proj_kernel, dim3(NTOK / 64, BATCH), blk, 0, stream,
                       cape, era5, Wq, bq, Wk, bk, Wv, bv, Qb, Kb, Vb);
    hipLaunchKernelGGL(attn_kernel, dim3((NTOK / 64) * KSPLIT * BATCH), dim3(128), 0, stream,
                       Qb, Kb, Vb, Op, Lp);
    hipLaunchKernelGGL(oproj_kernel, dim3(NTOK / 64, BATCH), blk, 0, stream,
                       Op, Lp, Wo, bo, (float*)d_out);
}

// Round 4
// 175.202 us; speedup vs baseline: 2.8180x; 1.5763x over previous
//
#include <hip/hip_runtime.h>

typedef unsigned short u16;
typedef __attribute__((ext_vector_type(8))) short short8;
typedef __attribute__((ext_vector_type(4))) float f32x4;
typedef __attribute__((ext_vector_type(16))) float f32x16;

constexpr int BATCH = 8, CC = 128, CE = 256, DIM = 128, NTOK = 4096;
constexpr int KSPLIT = 2, KTILES = NTOK / KSPLIT / 64;

#define DEV static __device__ __forceinline__

DEV u16 f2bf(float f) {
    union { float f; unsigned u; } v; v.f = f;
    unsigned r = (v.u + 0x7fffu + ((v.u >> 16) & 1u)) >> 16;
    return (u16)r;
}
DEV float bf2f(u16 h) {
    union { unsigned u; float f; } v; v.u = ((unsigned)h) << 16;
    return v.f;
}
DEV short8 mk8(unsigned a, unsigned b, unsigned c, unsigned d) {
    union { unsigned u[4]; short8 s; } t; t.u[0] = a; t.u[1] = b; t.u[2] = c; t.u[3] = d;
    return t.s;
}

// ---------------------------------------------------------------------------
// Kernel 0a: transpose+convert inputs: [B][C][N] f32 -> [B][N][C] bf16.
// grid (64 n-tiles, 6 c-tiles(2 cape+4 era5), 8 b), 256 thr.
// ---------------------------------------------------------------------------
__global__ __launch_bounds__(256)
void xpose_kernel(const float* __restrict__ cape, const float* __restrict__ era5,
                  u16* __restrict__ capeT, u16* __restrict__ era5T)
{
    __shared__ __align__(16) u16 sT[64 * 68];   // pitch 68: odd-dword banks, 8B aligned
    const int tid = threadIdx.x;
    const int nbase = blockIdx.x * 64;
    const int ct = blockIdx.y;
    const int b = blockIdx.z;

    const float* src; u16* dst; int pitch, c0;
    if (ct < 2) { src = cape + ((size_t)b * CC + ct * 64) * NTOK;
                  dst = capeT + (size_t)b * NTOK * CC; pitch = CC; c0 = ct * 64; }
    else        { src = era5 + ((size_t)b * CE + (ct - 2) * 64) * NTOK;
                  dst = era5T + (size_t)b * NTOK * CE; pitch = CE; c0 = (ct - 2) * 64; }

#pragma unroll
    for (int i = 0; i < 4; ++i) {
        int lin = tid + 256 * i;
        int c = lin >> 4, n4 = (lin & 15) * 4;
        float4 v = *(const float4*)&src[(size_t)c * NTOK + nbase + n4];
        ushort4 h; h.x = f2bf(v.x); h.y = f2bf(v.y); h.z = f2bf(v.z); h.w = f2bf(v.w);
        *(ushort4*)&sT[c * 68 + n4] = h;
    }
    __syncthreads();
#pragma unroll
    for (int i = 0; i < 2; ++i) {
        int lin = tid + 256 * i;
        int n = lin >> 3, cs = (lin & 7) * 8;
        short8 o;
#pragma unroll
        for (int j = 0; j < 8; ++j) o[j] = (short)sT[(cs + j) * 68 + n];
        *(short8*)&dst[(size_t)(nbase + n) * pitch + c0 + cs] = o;
    }
}

// ---------------------------------------------------------------------------
// Kernel 0b: convert Wq/Wk/Wv f32 -> bf16 (same [d][c] layout). grid 80x256x4.
// ---------------------------------------------------------------------------
__global__ __launch_bounds__(256)
void wconv_kernel(const float* __restrict__ Wq, const float* __restrict__ Wk,
                  const float* __restrict__ Wv, u16* __restrict__ Wqb,
                  u16* __restrict__ Wkb, u16* __restrict__ Wvb)
{
    int lin = (blockIdx.x * 256 + threadIdx.x) * 4;
    const float* s; u16* d; int off;
    if (lin < 16384)      { s = Wq; d = Wqb; off = lin; }
    else if (lin < 49152) { s = Wk; d = Wkb; off = lin - 16384; }
    else                  { s = Wv; d = Wvb; off = lin - 49152; }
    float4 v = *(const float4*)&s[off];
    ushort4 h; h.x = f2bf(v.x); h.y = f2bf(v.y); h.z = f2bf(v.z); h.w = f2bf(v.w);
    *(ushort4*)&d[off] = h;
}

// ---------------------------------------------------------------------------
// Kernel 1: MFMA QKV projection. OUT^T[n][d] = sum_c Xt[n][c] * W[d][c].
// A-frag = Xt rows (16B direct global), B-frag = W rows (16B direct global).
// Q,K stored [B][N][D]; V via per-wave LDS transpose -> [B][D][N].
// 4 waves; wave w owns d-block w. grid (64, 8).
// ---------------------------------------------------------------------------
__global__ __launch_bounds__(256)
void qkv_proj_kernel(const u16* __restrict__ capeT, const u16* __restrict__ era5T,
                     const u16* __restrict__ Wqb, const u16* __restrict__ Wkb,
                     const u16* __restrict__ Wvb, const float* __restrict__ bq,
                     const float* __restrict__ bk, const float* __restrict__ bv,
                     u16* __restrict__ Qb, u16* __restrict__ Kb, u16* __restrict__ Vb)
{
    __shared__ __align__(16) u16 sT[4][32 * 68];   // per-wave V transpose tile

    const int tid = threadIdx.x, lane = tid & 63, w = tid >> 6;
    const int l31 = lane & 31, half = lane >> 5;
    const int b = blockIdx.y, nbase = blockIdx.x * 64;
    const int d = w * 32 + l31;

    // ---- Q: C = 128, 8 k-steps
    f32x16 aq0, aq1;
#pragma unroll
    for (int r = 0; r < 16; ++r) { aq0[r] = 0.f; aq1[r] = 0.f; }
    {
        const u16* xr0 = capeT + ((size_t)b * NTOK + nbase + l31) * CC + half * 8;
        const u16* xr1 = xr0 + 32 * CC;
        const u16* wr  = Wqb + (size_t)d * CC + half * 8;
#pragma unroll
        for (int kc = 0; kc < 8; ++kc) {
            short8 a0 = *(const short8*)(xr0 + kc * 16);
            short8 a1 = *(const short8*)(xr1 + kc * 16);
            short8 bw = *(const short8*)(wr + kc * 16);
            aq0 = __builtin_amdgcn_mfma_f32_32x32x16_bf16(a0, bw, aq0, 0, 0, 0);
            aq1 = __builtin_amdgcn_mfma_f32_32x32x16_bf16(a1, bw, aq1, 0, 0, 0);
        }
    }
    {
        const float bias = bq[d];
        u16* q0 = Qb + ((size_t)b * NTOK + nbase) * DIM + d;
#pragma unroll
        for (int r = 0; r < 16; ++r) {
            const int nl = (r & 3) + 8 * (r >> 2) + 4 * half;
            q0[(size_t)nl * DIM] = f2bf(aq0[r] + bias);
            q0[(size_t)(nl + 32) * DIM] = f2bf(aq1[r] + bias);
        }
    }

    // ---- K & V fused: C = 256, 16 k-steps, shared A-frags
    f32x16 ak0, ak1, av0, av1;
#pragma unroll
    for (int r = 0; r < 16; ++r) { ak0[r] = 0.f; ak1[r] = 0.f; av0[r] = 0.f; av1[r] = 0.f; }
    {
        const u16* er0 = era5T + ((size_t)b * NTOK + nbase + l31) * CE + half * 8;
        const u16* er1 = er0 + 32 * CE;
        const u16* wkr = Wkb + (size_t)d * CE + half * 8;
        const u16* wvr = Wvb + (size_t)d * CE + half * 8;
#pragma unroll
        for (int kc = 0; kc < 16; ++kc) {
            short8 a0 = *(const short8*)(er0 + kc * 16);
            short8 a1 = *(const short8*)(er1 + kc * 16);
            short8 bwk = *(const short8*)(wkr + kc * 16);
            short8 bwv = *(const short8*)(wvr + kc * 16);
            ak0 = __builtin_amdgcn_mfma_f32_32x32x16_bf16(a0, bwk, ak0, 0, 0, 0);
            ak1 = __builtin_amdgcn_mfma_f32_32x32x16_bf16(a1, bwk, ak1, 0, 0, 0);
            av0 = __builtin_amdgcn_mfma_f32_32x32x16_bf16(a0, bwv, av0, 0, 0, 0);
            av1 = __builtin_amdgcn_mfma_f32_32x32x16_bf16(a1, bwv, av1, 0, 0, 0);
        }
    }
    {
        const float bias = bk[d];
        u16* k0 = Kb + ((size_t)b * NTOK + nbase) * DIM + d;
#pragma unroll
        for (int r = 0; r < 16; ++r) {
            const int nl = (r & 3) + 8 * (r >> 2) + 4 * half;
            k0[(size_t)nl * DIM] = f2bf(ak0[r] + bias);
            k0[(size_t)(nl + 32) * DIM] = f2bf(ak1[r] + bias);
        }
    }
    // V: frag rows = n, cols = d -> transpose via per-wave LDS (pitch 68)
    {
        const float bias = bv[d];
        u16* t = &sT[w][0];
#pragma unroll
        for (int r = 0; r < 16; ++r) {
            const int nl = (r & 3) + 8 * (r >> 2) + 4 * half;
            t[l31 * 68 + nl] = f2bf(av0[r] + bias);
            t[l31 * 68 + nl + 32] = f2bf(av1[r] + bias);
        }
#pragma unroll
        for (int i = 0; i < 4; ++i) {
            int rlin = lane + 64 * i;
            int dl = rlin >> 3, n8 = (rlin & 7) * 8;
            uint2 p0 = *(const uint2*)&t[dl * 68 + n8];
            uint2 p1 = *(const uint2*)&t[dl * 68 + n8 + 4];
            uint4 o = {p0.x, p0.y, p1.x, p1.y};
            *(uint4*)&Vb[((size_t)b * DIM + w * 32 + dl) * NTOK + nbase + n8] = o;
        }
    }
}

// ---------------------------------------------------------------------------
// Kernel 2: flash attention (unchanged from round 3).
// ---------------------------------------------------------------------------
__global__ __launch_bounds__(128)
void attn_kernel(const u16* __restrict__ Qb, const u16* __restrict__ Kb,
                 const u16* __restrict__ Vb, u16* __restrict__ Op,
                 float* __restrict__ Lp)
{
    __shared__ __align__(16) u16 sK[64 * 128];
    __shared__ __align__(16) u16 sV[128 * 64];

    const int tid = threadIdx.x;
    const int lane = tid & 63, wv = tid >> 6;
    const int l31 = lane & 31, half = lane >> 5;

    const int lin = blockIdx.x;
    const int swz = (lin & 7) * 128 + (lin >> 3);
    const int b = swz >> 7;
    const int rem = swz & 127;
    const int ks = rem >> 6;
    const int qtile = rem & 63;
    const int qbase = qtile * 64 + wv * 32;
    const int kbase = ks * (NTOK / KSPLIT);

    const float kScale = 0.088388347648318447f * 1.4426950408889634f;

    short8 aQ[8];
    {
        const u16* qrow = Qb + ((size_t)b * NTOK + qbase + l31) * DIM + half * 8;
#pragma unroll
        for (int s = 0; s < 8; ++s) aQ[s] = *(const short8*)&qrow[s * 16];
    }

    f32x16 O[4];
#pragma unroll
    for (int i = 0; i < 4; ++i)
#pragma unroll
        for (int r = 0; r < 16; ++r) O[i][r] = 0.f;
    float l_part = 0.f;

    const u16* Kbat = Kb + (size_t)b * NTOK * DIM;
    const u16* Vbat = Vb + (size_t)b * DIM * NTOK;

    for (int t = 0; t < KTILES; ++t) {
        {
            const u16* kb0 = Kbat + (size_t)(kbase + t * 64) * DIM;
#pragma unroll
            for (int i = 0; i < 8; ++i) {
                const int row = wv * 32 + i * 4 + (lane >> 4);
                const int p = lane & 15;
                const u16* g = kb0 + (size_t)row * DIM + ((p ^ (row & 7)) * 8);
                __builtin_amdgcn_global_load_lds(
                    (const __attribute__((address_space(1))) unsigned int*)g,
                    (__attribute__((address_space(3))) unsigned int*)&sK[(wv * 8 + i) * 512],
                    16, 0, 0);
            }
        }
        {
            const u16* vb0 = Vbat + kbase + t * 64;
#pragma unroll
            for (int i = 0; i < 8; ++i) {
                const int row = wv * 64 + i * 8 + (lane >> 3);
                const int p = lane & 7;
                const u16* g = vb0 + (size_t)row * NTOK + ((p ^ (row & 7)) * 8);
                __builtin_amdgcn_global_load_lds(
                    (const __attribute__((address_space(1))) unsigned int*)g,
                    (__attribute__((address_space(3))) unsigned int*)&sV[(wv * 8 + i) * 512],
                    16, 0, 0);
            }
        }
        __syncthreads();

        f32x16 S0, S1;
#pragma unroll
        for (int r = 0; r < 16; ++r) { S0[r] = 0.f; S1[r] = 0.f; }
        __builtin_amdgcn_s_setprio(1);
#pragma unroll
        for (int s = 0; s < 8; ++s) {
            const int pos = (((s * 2 + half) ^ (l31 & 7)) * 8);
            short8 k0 = *(const short8*)&sK[l31 * 128 + pos];
            short8 k1 = *(const short8*)&sK[(32 + l31) * 128 + pos];
            S0 = __builtin_amdgcn_mfma_f32_32x32x16_bf16(k0, aQ[s], S0, 0, 0, 0);
            S1 = __builtin_amdgcn_mfma_f32_32x32x16_bf16(k1, aQ[s], S1, 0, 0, 0);
        }
        __builtin_amdgcn_s_setprio(0);

        unsigned xm[8], ym[8];
#define SM_GROUP(m, Sb)                                                              \
        {                                                                            \
            float p0 = exp2f(Sb[(m & 3) * 4 + 0] * kScale);                          \
            float p1 = exp2f(Sb[(m & 3) * 4 + 1] * kScale);                          \
            float p2 = exp2f(Sb[(m & 3) * 4 + 2] * kScale);                          \
            float p3 = exp2f(Sb[(m & 3) * 4 + 3] * kScale);                          \
            l_part += (p0 + p1) + (p2 + p3);                                         \
            asm("v_cvt_pk_bf16_f32 %0, %1, %2" : "=v"(xm[m]) : "v"(p0), "v"(p1));    \
            asm("v_cvt_pk_bf16_f32 %0, %1, %2" : "=v"(ym[m]) : "v"(p2), "v"(p3));    \
        }
        SM_GROUP(0, S0) SM_GROUP(1, S0) SM_GROUP(2, S0) SM_GROUP(3, S0)
        SM_GROUP(4, S1) SM_GROUP(5, S1) SM_GROUP(6, S1) SM_GROUP(7, S1)
#undef SM_GROUP

        short8 pa[4];
#pragma unroll
        for (int s2 = 0; s2 < 4; ++s2) {
            unsigned xa = xm[2 * s2], xb = xm[2 * s2 + 1];
            unsigned ya = ym[2 * s2], yb = ym[2 * s2 + 1];
            asm("v_permlane32_swap_b32 %0, %1" : "+v"(xa), "+v"(xb));
            asm("v_permlane32_swap_b32 %0, %1" : "+v"(ya), "+v"(yb));
            pa[s2] = mk8(xa, ya, xb, yb);
        }

        __builtin_amdgcn_s_setprio(1);
#pragma unroll
        for (int dblk = 0; dblk < 4; ++dblk) {
            const int vrow = dblk * 32 + l31;
#pragma unroll
            for (int s2 = 0; s2 < 4; ++s2) {
                short8 v = *(const short8*)&sV[vrow * 64 + (((s2 * 2 + half) ^ (l31 & 7)) * 8)];
                O[dblk] = __builtin_amdgcn_mfma_f32_32x32x16_bf16(pa[s2], v, O[dblk], 0, 0, 0);
            }
        }
        __builtin_amdgcn_s_setprio(0);
        __syncthreads();
    }

    float l_tot = l_part + __shfl_xor(l_part, 32, 64);
    if (half == 0)
        Lp[(size_t)(ks * BATCH + b) * NTOK + qbase + l31] = l_tot;

    u16* obase = Op + ((size_t)(ks * BATCH + b) * NTOK + qbase) * DIM;
#pragma unroll
    for (int dblk = 0; dblk < 4; ++dblk)
#pragma unroll
        for (int r = 0; r < 16; ++r) {
            const int q = (r & 3) + 8 * (r >> 2) + 4 * half;
            obase[(size_t)q * DIM + dblk * 32 + l31] = f2bf(O[dblk][r]);
        }
}

// ---------------------------------------------------------------------------
// Kernel 3: combine split-K partials + output projection (unchanged).
// ---------------------------------------------------------------------------
__global__ __launch_bounds__(256)
void oproj_kernel(const u16* __restrict__ Op, const float* __restrict__ Lp,
                  const float* __restrict__ Wo, const float* __restrict__ bo,
                  float* __restrict__ Out)
{
    __shared__ __align__(16) u16 sA[128 * 72];
    __shared__ __align__(16) u16 sW[128 * 128];

    const int tid = threadIdx.x;
    const int b = blockIdx.y;
    const int nbase = blockIdx.x * 64;

#pragma unroll 4
    for (int i = 0; i < 64; ++i) {
        int idx = tid + 256 * i;
        int d = idx & 127, co = idx >> 7;
        sW[d * 128 + co] = f2bf(Wo[(size_t)co * DIM + d]);
    }
#pragma unroll
    for (int i = 0; i < 4; ++i) {
        int idx = tid + 256 * i;
        int c = idx & 15, n = idx >> 4;
        const size_t r0 = ((size_t)b * NTOK + nbase + n) * DIM + c * 8;
        const size_t r1 = ((size_t)(BATCH + b) * NTOK + nbase + n) * DIM + c * 8;
        uint4 v0 = *(const uint4*)&Op[r0];
        uint4 v1 = *(const uint4*)&Op[r1];
        float l = Lp[(size_t)b * NTOK + nbase + n] +
                  Lp[(size_t)(BATCH + b) * NTOK + nbase + n];
        float inv = 1.f / l;
        unsigned t0[4] = {v0.x, v0.y, v0.z, v0.w};
        unsigned t1[4] = {v1.x, v1.y, v1.z, v1.w};
#pragma unroll
        for (int j = 0; j < 8; ++j) {
            float a = bf2f((u16)(t0[j >> 1] >> ((j & 1) * 16)));
            float bq_ = bf2f((u16)(t1[j >> 1] >> ((j & 1) * 16)));
            sA[(c * 8 + j) * 72 + n] = f2bf((a + bq_) * inv);
        }
    }
    __syncthreads();

    const int nl = tid & 15, cg = tid >> 4;
    const int n0 = nl * 4, co0 = cg * 8;
    float acc[4][8];
#pragma unroll
    for (int i = 0; i < 4; ++i)
#pragma unroll
        for (int j = 0; j < 8; ++j) acc[i][j] = 0.f;

#pragma unroll 4
    for (int d = 0; d < 128; ++d) {
        ushort4 xs = *(const ushort4*)&sA[d * 72 + n0];
        short8 wvv = *(const short8*)&sW[d * 128 + co0];
        float x[4] = {bf2f(xs.x), bf2f(xs.y), bf2f(xs.z), bf2f(xs.w)};
        float wf[8];
#pragma unroll
        for (int j = 0; j < 8; ++j) wf[j] = bf2f((u16)wvv[j]);
#pragma unroll
        for (int i = 0; i < 4; ++i)
#pragma unroll
            for (int j = 0; j < 8; ++j) acc[i][j] += x[i] * wf[j];
    }

#pragma unroll
    for (int j = 0; j < 8; ++j) {
        float bb = bo[co0 + j];
        float4 o = {acc[0][j] + bb, acc[1][j] + bb, acc[2][j] + bb, acc[3][j] + bb};
        *(float4*)&Out[((size_t)b * DIM + co0 + j) * NTOK + nbase + n0] = o;
    }
}

// ---------------------------------------------------------------------------
extern "C" void kernel_launch(void* const* d_in, const int* in_sizes, int n_in,
                              void* d_out, int out_size, void* d_ws, size_t ws_size,
                              hipStream_t stream)
{
    const float* cape = (const float*)d_in[0];
    const float* era5 = (const float*)d_in[1];
    const float* Wq = (const float*)d_in[2];
    const float* bq = (const float*)d_in[3];
    const float* Wk = (const float*)d_in[4];
    const float* bk = (const float*)d_in[5];
    const float* Wv = (const float*)d_in[6];
    const float* bv = (const float*)d_in[7];
    const float* Wo = (const float*)d_in[8];
    const float* bo = (const float*)d_in[9];

    const size_t QKV = (size_t)BATCH * NTOK * DIM;
    u16* Qb  = (u16*)d_ws;
    u16* Kb  = Qb + QKV;
    u16* Vb  = Kb + QKV;
    u16* Wqb = Vb + QKV;
    u16* Wkb = Wqb + 16384;
    u16* Wvb = Wkb + 32768;
    u16* regionA = Wvb + 32768;
    // overlay 1 (lifetime: xpose..qkv_proj)
    u16* capeT = regionA;
    u16* era5T = capeT + QKV;            // QKV elems for capeT (B*N*128)
    // overlay 2 (lifetime: attn..oproj) — reuses the same region
    u16* Op = regionA;
    float* Lp = (float*)(Op + (size_t)KSPLIT * QKV);

    hipLaunchKernelGGL(xpose_kernel, dim3(64, 6, BATCH), dim3(256), 0, stream,
                       cape, era5, capeT, era5T);
    hipLaunchKernelGGL(wconv_kernel, dim3(80), dim3(256), 0, stream,
                       Wq, Wk, Wv, Wqb, Wkb, Wvb);
    hipLaunchKernelGGL(qkv_proj_kernel, dim3(64, BATCH), dim3(256), 0, stream,
                       capeT, era5T, Wqb, Wkb, Wvb, bq, bk, bv, Qb, Kb, Vb);
    hipLaunchKernelGGL(attn_kernel, dim3((NTOK / 64) * KSPLIT * BATCH), dim3(128), 0, stream,
                       Qb, Kb, Vb, Op, Lp);
    hipLaunchKernelGGL(oproj_kernel, dim3(64, BATCH), dim3(256), 0, stream,
                       Op, Lp, Wo, bo, (float*)d_out);
}

// Round 5
// 160.718 us; speedup vs baseline: 3.0719x; 1.0901x over previous
//
#include <hip/hip_runtime.h>

typedef unsigned short u16;
typedef __attribute__((ext_vector_type(8))) short short8;
typedef __attribute__((ext_vector_type(4))) float f32x4;
typedef __attribute__((ext_vector_type(16))) float f32x16;

constexpr int BATCH = 8, CC = 128, CE = 256, DIM = 128, NTOK = 4096;
constexpr int KSPLIT = 2, KTILES = NTOK / KSPLIT / 64;

#define DEV static __device__ __forceinline__

DEV u16 f2bf(float f) {
    union { float f; unsigned u; } v; v.f = f;
    unsigned r = (v.u + 0x7fffu + ((v.u >> 16) & 1u)) >> 16;
    return (u16)r;
}
DEV float bf2f(u16 h) {
    union { unsigned u; float f; } v; v.u = ((unsigned)h) << 16;
    return v.f;
}
DEV short8 mk8(unsigned a, unsigned b, unsigned c, unsigned d) {
    union { unsigned u[4]; short8 s; } t; t.u[0] = a; t.u[1] = b; t.u[2] = c; t.u[3] = d;
    return t.s;
}

// ---------------------------------------------------------------------------
// Kernel 0a: transpose+convert inputs: [B][C][N] f32 -> [B][N][C] bf16.
// ---------------------------------------------------------------------------
__global__ __launch_bounds__(256)
void xpose_kernel(const float* __restrict__ cape, const float* __restrict__ era5,
                  u16* __restrict__ capeT, u16* __restrict__ era5T)
{
    __shared__ __align__(16) u16 sT[64 * 68];
    const int tid = threadIdx.x;
    const int nbase = blockIdx.x * 64;
    const int ct = blockIdx.y;
    const int b = blockIdx.z;

    const float* src; u16* dst; int pitch, c0;
    if (ct < 2) { src = cape + ((size_t)b * CC + ct * 64) * NTOK;
                  dst = capeT + (size_t)b * NTOK * CC; pitch = CC; c0 = ct * 64; }
    else        { src = era5 + ((size_t)b * CE + (ct - 2) * 64) * NTOK;
                  dst = era5T + (size_t)b * NTOK * CE; pitch = CE; c0 = (ct - 2) * 64; }

#pragma unroll
    for (int i = 0; i < 4; ++i) {
        int lin = tid + 256 * i;
        int c = lin >> 4, n4 = (lin & 15) * 4;
        float4 v = *(const float4*)&src[(size_t)c * NTOK + nbase + n4];
        ushort4 h; h.x = f2bf(v.x); h.y = f2bf(v.y); h.z = f2bf(v.z); h.w = f2bf(v.w);
        *(ushort4*)&sT[c * 68 + n4] = h;
    }
    __syncthreads();
#pragma unroll
    for (int i = 0; i < 2; ++i) {
        int lin = tid + 256 * i;
        int n = lin >> 3, cs = (lin & 7) * 8;
        short8 o;
#pragma unroll
        for (int j = 0; j < 8; ++j) o[j] = (short)sT[(cs + j) * 68 + n];
        *(short8*)&dst[(size_t)(nbase + n) * pitch + c0 + cs] = o;
    }
}

// ---------------------------------------------------------------------------
// Kernel 0b: convert Wq/Wk/Wv f32 -> bf16.
// ---------------------------------------------------------------------------
__global__ __launch_bounds__(256)
void wconv_kernel(const float* __restrict__ Wq, const float* __restrict__ Wk,
                  const float* __restrict__ Wv, u16* __restrict__ Wqb,
                  u16* __restrict__ Wkb, u16* __restrict__ Wvb)
{
    int lin = (blockIdx.x * 256 + threadIdx.x) * 4;
    const float* s; u16* d; int off;
    if (lin < 16384)      { s = Wq; d = Wqb; off = lin; }
    else if (lin < 49152) { s = Wk; d = Wkb; off = lin - 16384; }
    else                  { s = Wv; d = Wvb; off = lin - 49152; }
    float4 v = *(const float4*)&s[off];
    ushort4 h; h.x = f2bf(v.x); h.y = f2bf(v.y); h.z = f2bf(v.z); h.w = f2bf(v.w);
    *(ushort4*)&d[off] = h;
}

// ---------------------------------------------------------------------------
// Kernel 1: MFMA QKV projection (unchanged from round 4).
// ---------------------------------------------------------------------------
__global__ __launch_bounds__(256)
void qkv_proj_kernel(const u16* __restrict__ capeT, const u16* __restrict__ era5T,
                     const u16* __restrict__ Wqb, const u16* __restrict__ Wkb,
                     const u16* __restrict__ Wvb, const float* __restrict__ bq,
                     const float* __restrict__ bk, const float* __restrict__ bv,
                     u16* __restrict__ Qb, u16* __restrict__ Kb, u16* __restrict__ Vb)
{
    __shared__ __align__(16) u16 sT[4][32 * 68];

    const int tid = threadIdx.x, lane = tid & 63, w = tid >> 6;
    const int l31 = lane & 31, half = lane >> 5;
    const int b = blockIdx.y, nbase = blockIdx.x * 64;
    const int d = w * 32 + l31;

    f32x16 aq0, aq1;
#pragma unroll
    for (int r = 0; r < 16; ++r) { aq0[r] = 0.f; aq1[r] = 0.f; }
    {
        const u16* xr0 = capeT + ((size_t)b * NTOK + nbase + l31) * CC + half * 8;
        const u16* xr1 = xr0 + 32 * CC;
        const u16* wr  = Wqb + (size_t)d * CC + half * 8;
#pragma unroll
        for (int kc = 0; kc < 8; ++kc) {
            short8 a0 = *(const short8*)(xr0 + kc * 16);
            short8 a1 = *(const short8*)(xr1 + kc * 16);
            short8 bw = *(const short8*)(wr + kc * 16);
            aq0 = __builtin_amdgcn_mfma_f32_32x32x16_bf16(a0, bw, aq0, 0, 0, 0);
            aq1 = __builtin_amdgcn_mfma_f32_32x32x16_bf16(a1, bw, aq1, 0, 0, 0);
        }
    }
    {
        const float bias = bq[d];
        u16* q0 = Qb + ((size_t)b * NTOK + nbase) * DIM + d;
#pragma unroll
        for (int r = 0; r < 16; ++r) {
            const int nl = (r & 3) + 8 * (r >> 2) + 4 * half;
            q0[(size_t)nl * DIM] = f2bf(aq0[r] + bias);
            q0[(size_t)(nl + 32) * DIM] = f2bf(aq1[r] + bias);
        }
    }

    f32x16 ak0, ak1, av0, av1;
#pragma unroll
    for (int r = 0; r < 16; ++r) { ak0[r] = 0.f; ak1[r] = 0.f; av0[r] = 0.f; av1[r] = 0.f; }
    {
        const u16* er0 = era5T + ((size_t)b * NTOK + nbase + l31) * CE + half * 8;
        const u16* er1 = er0 + 32 * CE;
        const u16* wkr = Wkb + (size_t)d * CE + half * 8;
        const u16* wvr = Wvb + (size_t)d * CE + half * 8;
#pragma unroll
        for (int kc = 0; kc < 16; ++kc) {
            short8 a0 = *(const short8*)(er0 + kc * 16);
            short8 a1 = *(const short8*)(er1 + kc * 16);
            short8 bwk = *(const short8*)(wkr + kc * 16);
            short8 bwv = *(const short8*)(wvr + kc * 16);
            ak0 = __builtin_amdgcn_mfma_f32_32x32x16_bf16(a0, bwk, ak0, 0, 0, 0);
            ak1 = __builtin_amdgcn_mfma_f32_32x32x16_bf16(a1, bwk, ak1, 0, 0, 0);
            av0 = __builtin_amdgcn_mfma_f32_32x32x16_bf16(a0, bwv, av0, 0, 0, 0);
            av1 = __builtin_amdgcn_mfma_f32_32x32x16_bf16(a1, bwv, av1, 0, 0, 0);
        }
    }
    {
        const float bias = bk[d];
        u16* k0 = Kb + ((size_t)b * NTOK + nbase) * DIM + d;
#pragma unroll
        for (int r = 0; r < 16; ++r) {
            const int nl = (r & 3) + 8 * (r >> 2) + 4 * half;
            k0[(size_t)nl * DIM] = f2bf(ak0[r] + bias);
            k0[(size_t)(nl + 32) * DIM] = f2bf(ak1[r] + bias);
        }
    }
    {
        const float bias = bv[d];
        u16* t = &sT[w][0];
#pragma unroll
        for (int r = 0; r < 16; ++r) {
            const int nl = (r & 3) + 8 * (r >> 2) + 4 * half;
            t[l31 * 68 + nl] = f2bf(av0[r] + bias);
            t[l31 * 68 + nl + 32] = f2bf(av1[r] + bias);
        }
#pragma unroll
        for (int i = 0; i < 4; ++i) {
            int rlin = lane + 64 * i;
            int dl = rlin >> 3, n8 = (rlin & 7) * 8;
            uint2 p0 = *(const uint2*)&t[dl * 68 + n8];
            uint2 p1 = *(const uint2*)&t[dl * 68 + n8 + 4];
            uint4 o = {p0.x, p0.y, p1.x, p1.y};
            *(uint4*)&Vb[((size_t)b * DIM + w * 32 + dl) * NTOK + nbase + n8] = o;
        }
    }
}

// ---------------------------------------------------------------------------
// Kernel 2: flash attention, double-buffered counted-vmcnt pipeline.
// 4 waves/block (QBLK=128, 32 q/wave), KVBLK=64, LDS 64KB (2 bufs),
// grid 512 = 2 blocks/CU. vmcnt(8) steady-state — never drains mid-loop.
// ---------------------------------------------------------------------------
__global__ __launch_bounds__(256, 2)
void attn_kernel(const u16* __restrict__ Qb, const u16* __restrict__ Kb,
                 const u16* __restrict__ Vb, u16* __restrict__ Op,
                 float* __restrict__ Lp)
{
    __shared__ __align__(16) u16 sK[2][64 * 128];   // [buf][ktok][d], chunk c^(ktok&7)
    __shared__ __align__(16) u16 sV[2][128 * 64];   // [buf][d][ktok], chunk c^(d&7)

    const int tid = threadIdx.x;
    const int lane = tid & 63, w = tid >> 6;
    const int l31 = lane & 31, half = lane >> 5;

    // XCD-aware decode: b = lin&7 == XCD id; each XCD's L2 holds one batch's K/V/Q.
    const int lin = blockIdx.x;
    const int b = lin & 7;
    const int r2 = lin >> 3;
    const int ks = r2 & 1;
    const int qt = r2 >> 1;                 // 0..31
    const int qbase = qt * 128 + w * 32;
    const int kbase = ks * (NTOK / KSPLIT);

    const float kScale = 0.088388347648318447f * 1.4426950408889634f;

    const u16* Kbat = Kb + (size_t)b * NTOK * DIM;
    const u16* Vbat = Vb + (size_t)b * DIM * NTOK;

    // 8 global_load_lds per wave per tile: 4 K-rows-groups + 4 V-rows-groups
#define STAGE(bufK, bufV, tt)                                                          \
    {                                                                                  \
        const u16* kb0 = Kbat + (size_t)(kbase + (tt) * 64) * DIM;                     \
        _Pragma("unroll")                                                              \
        for (int i = 0; i < 4; ++i) {                                                  \
            const int row = w * 16 + i * 4 + (lane >> 4);                              \
            const int p = lane & 15;                                                   \
            const u16* g = kb0 + (size_t)row * DIM + ((p ^ (row & 7)) * 8);            \
            __builtin_amdgcn_global_load_lds(                                          \
                (const __attribute__((address_space(1))) unsigned int*)g,              \
                (__attribute__((address_space(3))) unsigned int*)&(bufK)[(w * 16 + i * 4) * 128], \
                16, 0, 0);                                                             \
        }                                                                              \
        const u16* vb0 = Vbat + kbase + (tt) * 64;                                     \
        _Pragma("unroll")                                                              \
        for (int i = 0; i < 4; ++i) {                                                  \
            const int row = w * 32 + i * 8 + (lane >> 3);                              \
            const int p = lane & 7;                                                    \
            const u16* g = vb0 + (size_t)row * NTOK + ((p ^ (row & 7)) * 8);           \
            __builtin_amdgcn_global_load_lds(                                          \
                (const __attribute__((address_space(1))) unsigned int*)g,              \
                (__attribute__((address_space(3))) unsigned int*)&(bufV)[(w * 32 + i * 8) * 64], \
                16, 0, 0);                                                             \
        }                                                                              \
    }

    // Q fragments (issued first so the counted waits below stay conservative)
    short8 aQ[8];
    {
        const u16* qrow = Qb + ((size_t)b * NTOK + qbase + l31) * DIM + half * 8;
#pragma unroll
        for (int s = 0; s < 8; ++s) aQ[s] = *(const short8*)&qrow[s * 16];
    }

    // prologue: stage tiles 0 and 1
    STAGE(sK[0], sV[0], 0);
    STAGE(sK[1], sV[1], 1);

    f32x16 O[4];
#pragma unroll
    for (int i = 0; i < 4; ++i)
#pragma unroll
        for (int r = 0; r < 16; ++r) O[i][r] = 0.f;
    float l_part = 0.f;

    for (int t = 0; t < KTILES; ++t) {
        if (t + 1 < KTILES) asm volatile("s_waitcnt vmcnt(8)" ::: "memory");
        else                asm volatile("s_waitcnt vmcnt(0)" ::: "memory");
        __builtin_amdgcn_s_barrier();
        __builtin_amdgcn_sched_barrier(0);

        const u16* sKb = &sK[t & 1][0];
        const u16* sVb = &sV[t & 1][0];

        // ---- S^T = K Q^T
        f32x16 S0, S1;
#pragma unroll
        for (int r = 0; r < 16; ++r) { S0[r] = 0.f; S1[r] = 0.f; }
        __builtin_amdgcn_s_setprio(1);
#pragma unroll
        for (int s = 0; s < 8; ++s) {
            const int pos = (((s * 2 + half) ^ (l31 & 7)) * 8);
            short8 k0 = *(const short8*)&sKb[l31 * 128 + pos];
            short8 k1 = *(const short8*)&sKb[(32 + l31) * 128 + pos];
            S0 = __builtin_amdgcn_mfma_f32_32x32x16_bf16(k0, aQ[s], S0, 0, 0, 0);
            S1 = __builtin_amdgcn_mfma_f32_32x32x16_bf16(k1, aQ[s], S1, 0, 0, 0);
        }
        __builtin_amdgcn_s_setprio(0);

        // ---- softmax (no max tracking: |S*scale| < 1 statically) + bf16 pack
        unsigned xm[8], ym[8];
#define SM_GROUP(m, Sb)                                                              \
        {                                                                            \
            float p0 = exp2f(Sb[(m & 3) * 4 + 0] * kScale);                          \
            float p1 = exp2f(Sb[(m & 3) * 4 + 1] * kScale);                          \
            float p2 = exp2f(Sb[(m & 3) * 4 + 2] * kScale);                          \
            float p3 = exp2f(Sb[(m & 3) * 4 + 3] * kScale);                          \
            l_part += (p0 + p1) + (p2 + p3);                                         \
            asm("v_cvt_pk_bf16_f32 %0, %1, %2" : "=v"(xm[m]) : "v"(p0), "v"(p1));    \
            asm("v_cvt_pk_bf16_f32 %0, %1, %2" : "=v"(ym[m]) : "v"(p2), "v"(p3));    \
        }
        SM_GROUP(0, S0) SM_GROUP(1, S0) SM_GROUP(2, S0) SM_GROUP(3, S0)
        SM_GROUP(4, S1) SM_GROUP(5, S1) SM_GROUP(6, S1) SM_GROUP(7, S1)
#undef SM_GROUP

        short8 pa[4];
#pragma unroll
        for (int s2 = 0; s2 < 4; ++s2) {
            unsigned xa = xm[2 * s2], xb = xm[2 * s2 + 1];
            unsigned ya = ym[2 * s2], yb = ym[2 * s2 + 1];
            asm("v_permlane32_swap_b32 %0, %1" : "+v"(xa), "+v"(xb));
            asm("v_permlane32_swap_b32 %0, %1" : "+v"(ya), "+v"(yb));
            pa[s2] = mk8(xa, ya, xb, yb);
        }

        // ---- O += P V
        __builtin_amdgcn_s_setprio(1);
#pragma unroll
        for (int dblk = 0; dblk < 4; ++dblk) {
            const int vrow = dblk * 32 + l31;
#pragma unroll
            for (int s2 = 0; s2 < 4; ++s2) {
                short8 v = *(const short8*)&sVb[vrow * 64 + (((s2 * 2 + half) ^ (l31 & 7)) * 8)];
                O[dblk] = __builtin_amdgcn_mfma_f32_32x32x16_bf16(pa[s2], v, O[dblk], 0, 0, 0);
            }
        }
        __builtin_amdgcn_s_setprio(0);

        __builtin_amdgcn_sched_barrier(0);
        __builtin_amdgcn_s_barrier();        // all waves done reading buf[t&1]
        __builtin_amdgcn_sched_barrier(0);
        if (t + 2 < KTILES) STAGE(sK[t & 1], sV[t & 1], t + 2);
    }
#undef STAGE

    // ---- epilogue: store UNNORMALIZED partials
    float l_tot = l_part + __shfl_xor(l_part, 32, 64);
    if (half == 0)
        Lp[(size_t)(ks * BATCH + b) * NTOK + qbase + l31] = l_tot;

    u16* obase = Op + ((size_t)(ks * BATCH + b) * NTOK + qbase) * DIM;
#pragma unroll
    for (int dblk = 0; dblk < 4; ++dblk)
#pragma unroll
        for (int r = 0; r < 16; ++r) {
            const int q = (r & 3) + 8 * (r >> 2) + 4 * half;
            obase[(size_t)q * DIM + dblk * 32 + l31] = f2bf(O[dblk][r]);
        }
}

// ---------------------------------------------------------------------------
// Kernel 3: combine split-K partials + output projection (unchanged).
// ---------------------------------------------------------------------------
__global__ __launch_bounds__(256)
void oproj_kernel(const u16* __restrict__ Op, const float* __restrict__ Lp,
                  const float* __restrict__ Wo, const float* __restrict__ bo,
                  float* __restrict__ Out)
{
    __shared__ __align__(16) u16 sA[128 * 72];
    __shared__ __align__(16) u16 sW[128 * 128];

    const int tid = threadIdx.x;
    const int b = blockIdx.y;
    const int nbase = blockIdx.x * 64;

#pragma unroll 4
    for (int i = 0; i < 64; ++i) {
        int idx = tid + 256 * i;
        int d = idx & 127, co = idx >> 7;
        sW[d * 128 + co] = f2bf(Wo[(size_t)co * DIM + d]);
    }
#pragma unroll
    for (int i = 0; i < 4; ++i) {
        int idx = tid + 256 * i;
        int c = idx & 15, n = idx >> 4;
        const size_t r0 = ((size_t)b * NTOK + nbase + n) * DIM + c * 8;
        const size_t r1 = ((size_t)(BATCH + b) * NTOK + nbase + n) * DIM + c * 8;
        uint4 v0 = *(const uint4*)&Op[r0];
        uint4 v1 = *(const uint4*)&Op[r1];
        float l = Lp[(size_t)b * NTOK + nbase + n] +
                  Lp[(size_t)(BATCH + b) * NTOK + nbase + n];
        float inv = 1.f / l;
        unsigned t0[4] = {v0.x, v0.y, v0.z, v0.w};
        unsigned t1[4] = {v1.x, v1.y, v1.z, v1.w};
#pragma unroll
        for (int j = 0; j < 8; ++j) {
            float a = bf2f((u16)(t0[j >> 1] >> ((j & 1) * 16)));
            float bq_ = bf2f((u16)(t1[j >> 1] >> ((j & 1) * 16)));
            sA[(c * 8 + j) * 72 + n] = f2bf((a + bq_) * inv);
        }
    }
    __syncthreads();

    const int nl = tid & 15, cg = tid >> 4;
    const int n0 = nl * 4, co0 = cg * 8;
    float acc[4][8];
#pragma unroll
    for (int i = 0; i < 4; ++i)
#pragma unroll
        for (int j = 0; j < 8; ++j) acc[i][j] = 0.f;

#pragma unroll 4
    for (int d = 0; d < 128; ++d) {
        ushort4 xs = *(const ushort4*)&sA[d * 72 + n0];
        short8 wvv = *(const short8*)&sW[d * 128 + co0];
        float x[4] = {bf2f(xs.x), bf2f(xs.y), bf2f(xs.z), bf2f(xs.w)};
        float wf[8];
#pragma unroll
        for (int j = 0; j < 8; ++j) wf[j] = bf2f((u16)wvv[j]);
#pragma unroll
        for (int i = 0; i < 4; ++i)
#pragma unroll
            for (int j = 0; j < 8; ++j) acc[i][j] += x[i] * wf[j];
    }

#pragma unroll
    for (int j = 0; j < 8; ++j) {
        float bb = bo[co0 + j];
        float4 o = {acc[0][j] + bb, acc[1][j] + bb, acc[2][j] + bb, acc[3][j] + bb};
        *(float4*)&Out[((size_t)b * DIM + co0 + j) * NTOK + nbase + n0] = o;
    }
}

// ---------------------------------------------------------------------------
extern "C" void kernel_launch(void* const* d_in, const int* in_sizes, int n_in,
                              void* d_out, int out_size, void* d_ws, size_t ws_size,
                              hipStream_t stream)
{
    const float* cape = (const float*)d_in[0];
    const float* era5 = (const float*)d_in[1];
    const float* Wq = (const float*)d_in[2];
    const float* bq = (const float*)d_in[3];
    const float* Wk = (const float*)d_in[4];
    const float* bk = (const float*)d_in[5];
    const float* Wv = (const float*)d_in[6];
    const float* bv = (const float*)d_in[7];
    const float* Wo = (const float*)d_in[8];
    const float* bo = (const float*)d_in[9];

    const size_t QKV = (size_t)BATCH * NTOK * DIM;
    u16* Qb  = (u16*)d_ws;
    u16* Kb  = Qb + QKV;
    u16* Vb  = Kb + QKV;
    u16* Wqb = Vb + QKV;
    u16* Wkb = Wqb + 16384;
    u16* Wvb = Wkb + 32768;
    u16* regionA = Wvb + 32768;
    u16* capeT = regionA;
    u16* era5T = capeT + QKV;
    u16* Op = regionA;
    float* Lp = (float*)(Op + (size_t)KSPLIT * QKV);

    hipLaunchKernelGGL(xpose_kernel, dim3(64, 6, BATCH), dim3(256), 0, stream,
                       cape, era5, capeT, era5T);
    hipLaunchKernelGGL(wconv_kernel, dim3(80), dim3(256), 0, stream,
                       Wq, Wk, Wv, Wqb, Wkb, Wvb);
    hipLaunchKernelGGL(qkv_proj_kernel, dim3(64, BATCH), dim3(256), 0, stream,
                       capeT, era5T, Wqb, Wkb, Wvb, bq, bk, bv, Qb, Kb, Vb);
    hipLaunchKernelGGL(attn_kernel, dim3((NTOK / 128) * KSPLIT * BATCH), dim3(256), 0, stream,
                       Qb, Kb, Vb, Op, Lp);
    hipLaunchKernelGGL(oproj_kernel, dim3(64, BATCH), dim3(256), 0, stream,
                       Op, Lp, Wo, bo, (float*)d_out);
}